// Round 10
// baseline (102.564 us; speedup 1.0000x reference)
//
#include <hip/hip_runtime.h>
#include <math.h>

#define NB 32
#define NL 2048
#define NH 8
#define NE 64
#define NM 64
#define MRI 128          // 2*NM (re stacked over im)
#define BK 128           // K per chunk
#define NCH 16           // 2048 / BK

typedef __attribute__((ext_vector_type(8))) __bf16 bf16x8;
typedef __attribute__((ext_vector_type(2))) __bf16 bf16x2;
typedef __attribute__((ext_vector_type(8))) unsigned short us8;
typedef __attribute__((ext_vector_type(4))) float f32x4;
typedef __attribute__((ext_vector_type(16))) float f32x16;

__device__ __forceinline__ unsigned short f2bf(float x) {
  unsigned int u = __builtin_bit_cast(unsigned int, x);
  u = (u + 0x7fffu + ((u >> 16) & 1u)) >> 16;
  return (unsigned short)u;
}
__device__ __forceinline__ unsigned int pk2(float lo, float hi) {
  bf16x2 v;
  v[0] = (__bf16)lo;
  v[1] = (__bf16)hi;
  return __builtin_bit_cast(unsigned int, v);
}
__device__ __forceinline__ void gll16(const void* g, void* l) {
  __builtin_amdgcn_global_load_lds(
      (const __attribute__((address_space(1))) void*)g,
      (__attribute__((address_space(3))) void*)l, 16, 0, 0);
}

// ---------------- tables ----------------
// T  [128][2048] bf16 : row m = cos(2pi*f_m*l/L); row 64+m = -sin(...)
// IT [2048][128] bf16 : col m = s_m*cos(2pi*m*l'/L); col 64+m = -s_m*sin(...)
__global__ void tables_k(const int* __restrict__ idx,
                         unsigned short* __restrict__ T, unsigned short* __restrict__ IT) {
  int gid = blockIdx.x * blockDim.x + threadIdx.x;  // 0..262143
  const float w0 = 6.283185307179586f / (float)NL;
  {
    int row = gid >> 11, l = gid & (NL - 1);
    int m = row & 63;
    int f = idx[m];
    float s, c;
    sincosf((float)((f * l) & (NL - 1)) * w0, &s, &c);
    T[gid] = f2bf(row < 64 ? c : -s);
  }
  {
    int lp = gid >> 7, k = gid & 127;
    int m = k & 63;
    float s, c;
    sincosf((float)((m * lp) & (NL - 1)) * w0, &s, &c);
    float v = (k < 64) ? ((m == 0 ? 1.0f : 2.0f) / (float)NL) * c
                       : (m == 0 ? 0.0f : (-2.0f / (float)NL) * s);
    IT[gid] = f2bf(v);
  }
}

// ---------------- fused per-(b,h), 256 blocks x 1024 thr ----------------
// LDS: Ab dbuf 2x32768 @0 (256B rows, XOR (row&7)<<4)
//      Bb dbuf 2x16384 @65536 ([e 64][l 128] bf16 256B rows, XOR (e^(e>>2))&7 <<4)
//      after P1: Xs [128][272B] @0 ; OtB [64][256B] @34816
__global__ __launch_bounds__(1024) void fused_k(const float* __restrict__ q,
                                                const unsigned short* __restrict__ T,
                                                const unsigned short* __restrict__ IT,
                                                const float* __restrict__ wr,
                                                const float* __restrict__ wi,
                                                float* __restrict__ out) {
  __shared__ __align__(16) char smem[98304];
  int t = threadIdx.x, lane = t & 63, wid = t >> 6;
  int h = blockIdx.x & 7, b = blockIdx.x >> 3;

  // ================= P1: DFT  X = T * q =================
  {
    char* A0 = smem;
    char* A1 = smem + 32768;
    char* B0 = smem + 65536;
    char* B1 = smem + 65536 + 16384;
    const float* qb = q + ((size_t)b * NL * NH + h) * NE;  // q[b][l][h][e]
    int mh = wid >> 2, ehh = wid & 3;
    int eq = t & 15, lq = t >> 4;   // staging: e-quad (coalesced), l-pair 0..63
    f32x4 acc[2] = {};
    f32x4 qA[2], qB[2];

    auto qload = [&](int c, f32x4* qr) {
#pragma unroll
      for (int p = 0; p < 2; ++p)
        qr[p] = *(const f32x4*)(qb + (size_t)(c * BK + lq * 2 + p) * (NH * NE) + eq * 4);
    };
    auto writesB = [&](const f32x4* qr, char* bb) {
#pragma unroll
      for (int j = 0; j < 4; ++j) {
        int e = eq * 4 + j;
        int sw = ((e ^ (e >> 2)) & 7) << 4;
        *(unsigned int*)(bb + ((e * 256 + lq * 4) ^ sw)) = pk2(qr[0][j], qr[1][j]);
      }
    };
    auto stageA = [&](char* ab, int c) {
#pragma unroll
      for (int n = 0; n < 2; ++n) {
        int lin = n * 16384 + t * 16;
        int row = lin >> 8;
        int colb = (lin & 255) ^ ((row & 7) << 4);   // pre-swizzled source
        gll16((const char*)T + (size_t)row * (NL * 2) + (size_t)c * 256 + colb, ab + lin);
      }
    };
    auto compute = [&](const char* ab, const char* bb) {
#pragma unroll
      for (int ks2 = 0; ks2 < 4; ++ks2) {
        int e = ehh * 16 + (lane & 15);
        int bsw = ((e ^ (e >> 2)) & 7) << 4;
        int boff = (e * 256 + ks2 * 64 + (lane >> 4) * 16) ^ bsw;
        bf16x8 bfr = __builtin_bit_cast(bf16x8, *(const us8*)(bb + boff));
#pragma unroll
        for (int fm = 0; fm < 2; ++fm) {
          int row = mh * 32 + fm * 16 + (lane & 15);
          int aoff = (row * 256 + ks2 * 64 + (lane >> 4) * 16) ^ ((row & 7) << 4);
          bf16x8 afr = __builtin_bit_cast(bf16x8, *(const us8*)(ab + aoff));
          acc[fm] = __builtin_amdgcn_mfma_f32_16x16x32_bf16(afr, bfr, acc[fm], 0, 0, 0);
        }
      }
    };

    // prologue
    stageA(A0, 0);
    qload(0, qA);
    qload(1, qB);
    writesB(qA, B0);                          // waits q0 (drains gllA0 too, in-order)
    asm volatile("s_waitcnt vmcnt(2)" ::: "memory");  // keep q1 in flight
    __builtin_amdgcn_sched_barrier(0);
    asm volatile("s_waitcnt lgkmcnt(0)" ::: "memory");
    __builtin_amdgcn_s_barrier();
    // main loop: ONE barrier per chunk; q prefetched 2 chunks ahead
    for (int c = 0; c < 14; c += 2) {
      // chunk c (A0,B0)
      stageA(A1, c + 1);
      qload(c + 2, qA);
      compute(A0, B0);
      writesB(qB, B1);                        // q(c+1)
      asm volatile("s_waitcnt vmcnt(2)" ::: "memory");  // drain gllA(c+1); keep q(c+2)
      __builtin_amdgcn_sched_barrier(0);
      asm volatile("s_waitcnt lgkmcnt(0)" ::: "memory");
      __builtin_amdgcn_s_barrier();
      // chunk c+1 (A1,B1)
      stageA(A0, c + 2);
      qload(c + 3, qB);
      compute(A1, B1);
      writesB(qA, B0);                        // q(c+2)
      asm volatile("s_waitcnt vmcnt(2)" ::: "memory");  // drain gllA(c+2); keep q(c+3)
      __builtin_amdgcn_sched_barrier(0);
      asm volatile("s_waitcnt lgkmcnt(0)" ::: "memory");
      __builtin_amdgcn_s_barrier();
    }
    // chunk 14 (A0,B0)
    stageA(A1, 15);
    compute(A0, B0);
    writesB(qB, B1);                          // q15
    asm volatile("s_waitcnt vmcnt(0)" ::: "memory");
    __builtin_amdgcn_sched_barrier(0);
    asm volatile("s_waitcnt lgkmcnt(0)" ::: "memory");
    __builtin_amdgcn_s_barrier();
    // chunk 15 (A1,B1)
    compute(A1, B1);
    __syncthreads();
    // acc -> Xs fp32 [128 m_ri][272B rows], XOR ((row>>3)&7)<<4
#pragma unroll
    for (int fm = 0; fm < 2; ++fm)
#pragma unroll
      for (int r4 = 0; r4 < 4; ++r4) {
        int row = mh * 32 + fm * 16 + (lane >> 4) * 4 + r4;
        int col = ehh * 16 + (lane & 15);
        int off = (row * 272 + col * 4) ^ (((row >> 3) & 7) << 4);
        *(float*)(smem + off) = acc[fm][r4];
      }
  }
  __syncthreads();

  // ================= P2: mix (fp32 VALU, f32 W direct from L2) =================
  {
    char* OtB = smem + 34816;          // [64 o][128 m_ri] bf16, 256B rows, XOR (o&7)<<4
    int o = t >> 4, mq = t & 15;       // thread: 1 o, 4 m (m = mq*4+mi)
    const float* wrp = wr + (size_t)h * 262144 + (size_t)o * 64 + mq * 4;  // [i][o][m]
    const float* wip = wi + (size_t)h * 262144 + (size_t)o * 64 + mq * 4;
    float orr[4] = {}, oii[4] = {};
    for (int ib = 0; ib < 16; ++ib) {
      f32x4 xr4[4], xi4[4];
#pragma unroll
      for (int mi = 0; mi < 4; ++mi) {
        int m = mq * 4 + mi;
        xr4[mi] = *(const f32x4*)(smem + ((m * 272 + ib * 16) ^ (((m >> 3) & 7) << 4)));
        xi4[mi] = *(const f32x4*)(smem + (((64 + m) * 272 + ib * 16) ^ (((m >> 3) & 7) << 4)));
      }
      f32x4 wr4[4], wi4[4];
#pragma unroll
      for (int ii = 0; ii < 4; ++ii) {
        int i = ib * 4 + ii;
        wr4[ii] = *(const f32x4*)(wrp + (size_t)i * 4096);
        wi4[ii] = *(const f32x4*)(wip + (size_t)i * 4096);
      }
#pragma unroll
      for (int ii = 0; ii < 4; ++ii)
#pragma unroll
        for (int mi = 0; mi < 4; ++mi) {
          orr[mi] += xr4[mi][ii] * wr4[ii][mi] - xi4[mi][ii] * wi4[ii][mi];
          oii[mi] += xr4[mi][ii] * wi4[ii][mi] + xi4[mi][ii] * wr4[ii][mi];
        }
    }
    uint2 vr = make_uint2(pk2(orr[0], orr[1]), pk2(orr[2], orr[3]));
    uint2 vi = make_uint2(pk2(oii[0], oii[1]), pk2(oii[2], oii[3]));
    *(uint2*)(OtB + ((o * 256 + mq * 8) ^ ((o & 7) << 4))) = vr;
    *(uint2*)(OtB + ((o * 256 + 128 + mq * 8) ^ ((o & 7) << 4))) = vi;
  }
  __syncthreads();

  // ================= P3: iDFT  out = Ot * IT^T =================
  {
    const char* OtB = smem + 34816;
    bf16x8 af[2][8];
#pragma unroll
    for (int rg2 = 0; rg2 < 2; ++rg2)
#pragma unroll
      for (int ks = 0; ks < 8; ++ks) {
        int row = rg2 * 32 + (lane & 31);
        int off = (row * 256 + ks * 32 + (lane >> 5) * 16) ^ ((row & 7) << 4);
        af[rg2][ks] = __builtin_bit_cast(bf16x8, *(const us8*)(OtB + off));
      }
    float* ob = out + ((size_t)(b * 8 + h) * 64) * NL;
    int l0 = wid * 128;
    for (int ct = 0; ct < 4; ++ct) {
      int lr = l0 + ct * 32 + (lane & 31);
      f32x16 aE[2] = {}, aO[2] = {};   // even/odd-ks chains (4 independent)
#pragma unroll
      for (int ks = 0; ks < 8; ks += 2) {
        bf16x8 bv0 = __builtin_bit_cast(
            bf16x8, *(const us8*)(IT + (size_t)lr * MRI + ks * 16 + (lane >> 5) * 8));
        bf16x8 bv1 = __builtin_bit_cast(
            bf16x8, *(const us8*)(IT + (size_t)lr * MRI + (ks + 1) * 16 + (lane >> 5) * 8));
        aE[0] = __builtin_amdgcn_mfma_f32_32x32x16_bf16(af[0][ks], bv0, aE[0], 0, 0, 0);
        aE[1] = __builtin_amdgcn_mfma_f32_32x32x16_bf16(af[1][ks], bv0, aE[1], 0, 0, 0);
        aO[0] = __builtin_amdgcn_mfma_f32_32x32x16_bf16(af[0][ks + 1], bv1, aO[0], 0, 0, 0);
        aO[1] = __builtin_amdgcn_mfma_f32_32x32x16_bf16(af[1][ks + 1], bv1, aO[1], 0, 0, 0);
      }
#pragma unroll
      for (int rg2 = 0; rg2 < 2; ++rg2) {
        f32x16 a2 = aE[rg2] + aO[rg2];
#pragma unroll
        for (int rg = 0; rg < 16; ++rg) {
          int row = rg2 * 32 + ((rg & 3) + 8 * (rg >> 2) + 4 * (lane >> 5));
          ob[(size_t)row * NL + lr] = a2[rg];
        }
      }
    }
  }
}

extern "C" void kernel_launch(void* const* d_in, const int* in_sizes, int n_in,
                              void* d_out, int out_size, void* d_ws, size_t ws_size,
                              hipStream_t stream) {
  const float* q = (const float*)d_in[0];
  const float* wr = (const float*)d_in[3];
  const float* wi = (const float*)d_in[4];
  const int* idx = (const int*)d_in[5];
  float* out = (float*)d_out;
  char* ws = (char*)d_ws;

  constexpr size_t TBYTES = (size_t)MRI * NL * 2;   // 512 KB per table
  constexpr size_t NEED = 2 * TBYTES;
  if (ws_size < NEED) return;

  unsigned short* T = (unsigned short*)ws;
  unsigned short* IT = (unsigned short*)(ws + TBYTES);

  hipLaunchKernelGGL(tables_k, dim3(1024), dim3(256), 0, stream, idx, T, IT);
  hipLaunchKernelGGL(fused_k, dim3(NB * NH), dim3(1024), 0, stream, q, T, IT, wr, wi, out);
}

// Round 11
// 100.327 us; speedup vs baseline: 1.0223x; 1.0223x over previous
//
#include <hip/hip_runtime.h>
#include <math.h>

#define NB 32
#define NL 2048
#define NH 8
#define NE 64
#define NM 64
#define MRI 128          // 2*NM (re stacked over im)
#define BK 128           // K per chunk
#define NCH 16           // 2048 / BK

typedef __attribute__((ext_vector_type(8))) __bf16 bf16x8;
typedef __attribute__((ext_vector_type(2))) __bf16 bf16x2;
typedef __attribute__((ext_vector_type(8))) unsigned short us8;
typedef __attribute__((ext_vector_type(4))) unsigned short us4;
typedef __attribute__((ext_vector_type(4))) float f32x4;
typedef __attribute__((ext_vector_type(16))) float f32x16;

__device__ __forceinline__ unsigned short f2bf(float x) {
  unsigned int u = __builtin_bit_cast(unsigned int, x);
  u = (u + 0x7fffu + ((u >> 16) & 1u)) >> 16;
  return (unsigned short)u;
}
__device__ __forceinline__ float bf2f(unsigned short u) {
  return __builtin_bit_cast(float, (unsigned int)u << 16);
}
__device__ __forceinline__ unsigned int pk2(float lo, float hi) {
  bf16x2 v;
  v[0] = (__bf16)lo;
  v[1] = (__bf16)hi;
  return __builtin_bit_cast(unsigned int, v);
}
__device__ __forceinline__ void gll16(const void* g, void* l) {
  __builtin_amdgcn_global_load_lds(
      (const __attribute__((address_space(1))) void*)g,
      (__attribute__((address_space(3))) void*)l, 16, 0, 0);
}

// ---------------- tables + W->bf16 ----------------
// T  [128][2048] bf16 : row m = cos(2pi*f_m*l/L); row 64+m = -sin(...)
// IT [2048][128] bf16 : col m = s_m*cos(2pi*m*l'/L); col 64+m = -s_m*sin(...)
// WB r/i: w_real/imag [h][i][o][m] -> bf16, same layout (W[h]=4MB -> L2-resident/XCD)
__global__ void tables_k(const int* __restrict__ idx,
                         const float* __restrict__ wr, const float* __restrict__ wi,
                         unsigned short* __restrict__ T, unsigned short* __restrict__ IT,
                         unsigned short* __restrict__ WBr, unsigned short* __restrict__ WBi) {
  int gid = blockIdx.x * blockDim.x + threadIdx.x;  // 0..262143
  const float w0 = 6.283185307179586f / (float)NL;
  {
    int row = gid >> 11, l = gid & (NL - 1);
    int m = row & 63;
    int f = idx[m];
    float s, c;
    sincosf((float)((f * l) & (NL - 1)) * w0, &s, &c);
    T[gid] = f2bf(row < 64 ? c : -s);
  }
  {
    int lp = gid >> 7, k = gid & 127;
    int m = k & 63;
    float s, c;
    sincosf((float)((m * lp) & (NL - 1)) * w0, &s, &c);
    float v = (k < 64) ? ((m == 0 ? 1.0f : 2.0f) / (float)NL) * c
                       : (m == 0 ? 0.0f : (-2.0f / (float)NL) * s);
    IT[gid] = f2bf(v);
  }
  {
    const float2* wr2 = (const float2*)wr;
    const float2* wi2 = (const float2*)wi;
    unsigned int* obr = (unsigned int*)WBr;
    unsigned int* obi = (unsigned int*)WBi;
#pragma unroll
    for (int r = 0; r < 4; ++r) {
      int j = r * 262144 + gid;
      float2 a = wr2[j];
      float2 b2 = wi2[j];
      obr[j] = pk2(a.x, a.y);
      obi[j] = pk2(b2.x, b2.y);
    }
  }
}

// ---------------- fused per-(b,h), 256 blocks x 1024 thr ----------------
// LDS: Ab dbuf 2x32768 @0 (256B rows, XOR (row&7)<<4)
//      Bb dbuf 2x16384 @65536 ([e 64][l 128] bf16 256B rows, XOR ((e^(e>>2))&7)<<4)
//      after P1: Xs [128][272B] @0 (XOR ((m>>3)&7)<<4) ; OtB [64][256B] @34816 (XOR (o&15)<<4)
__global__ __launch_bounds__(1024) void fused_k(const float* __restrict__ q,
                                                const unsigned short* __restrict__ T,
                                                const unsigned short* __restrict__ IT,
                                                const unsigned short* __restrict__ WBr,
                                                const unsigned short* __restrict__ WBi,
                                                float* __restrict__ out) {
  __shared__ __align__(16) char smem[98304];
  int t = threadIdx.x, lane = t & 63, wid = t >> 6;
  int h = blockIdx.x & 7, b = blockIdx.x >> 3;

  // ================= P1: DFT  X = T * q =================
  {
    char* A0 = smem;
    char* A1 = smem + 32768;
    char* B0 = smem + 65536;
    char* B1 = smem + 65536 + 16384;
    const float* qb = q + ((size_t)b * NL * NH + h) * NE;  // q[b][l][h][e]
    int mh = wid >> 2, ehh = wid & 3;
    int eq = t & 15, lq = t >> 4;   // staging: e-quad (coalesced), l-pair 0..63
    f32x4 acc[2] = {};
    f32x4 qA[2], qB[2];

    auto qload = [&](int c, f32x4* qr) {
#pragma unroll
      for (int p = 0; p < 2; ++p)
        qr[p] = *(const f32x4*)(qb + (size_t)(c * BK + lq * 2 + p) * (NH * NE) + eq * 4);
    };
    auto writesB = [&](const f32x4* qr, char* bb) {
#pragma unroll
      for (int j = 0; j < 4; ++j) {
        int e = eq * 4 + j;
        int sw = ((e ^ (e >> 2)) & 7) << 4;
        *(unsigned int*)(bb + ((e * 256 + lq * 4) ^ sw)) = pk2(qr[0][j], qr[1][j]);
      }
    };
    auto stageA = [&](char* ab, int c) {
#pragma unroll
      for (int n = 0; n < 2; ++n) {
        int lin = n * 16384 + t * 16;
        int row = lin >> 8;
        int colb = (lin & 255) ^ ((row & 7) << 4);   // pre-swizzled source
        gll16((const char*)T + (size_t)row * (NL * 2) + (size_t)c * 256 + colb, ab + lin);
      }
    };
    auto compute = [&](const char* ab, const char* bb) {
#pragma unroll
      for (int ks2 = 0; ks2 < 4; ++ks2) {
        int e = ehh * 16 + (lane & 15);
        int bsw = ((e ^ (e >> 2)) & 7) << 4;
        int boff = (e * 256 + ks2 * 64 + (lane >> 4) * 16) ^ bsw;
        bf16x8 bfr = __builtin_bit_cast(bf16x8, *(const us8*)(bb + boff));
#pragma unroll
        for (int fm = 0; fm < 2; ++fm) {
          int row = mh * 32 + fm * 16 + (lane & 15);
          int aoff = (row * 256 + ks2 * 64 + (lane >> 4) * 16) ^ ((row & 7) << 4);
          bf16x8 afr = __builtin_bit_cast(bf16x8, *(const us8*)(ab + aoff));
          acc[fm] = __builtin_amdgcn_mfma_f32_16x16x32_bf16(afr, bfr, acc[fm], 0, 0, 0);
        }
      }
    };

    // prologue
    stageA(A0, 0);
    qload(0, qA);
    qload(1, qB);
    writesB(qA, B0);
    asm volatile("s_waitcnt vmcnt(2)" ::: "memory");  // keep q1 in flight
    __builtin_amdgcn_sched_barrier(0);
    asm volatile("s_waitcnt lgkmcnt(0)" ::: "memory");
    __builtin_amdgcn_s_barrier();
    // main loop: ONE barrier per chunk; q prefetched 2 chunks ahead
    for (int c = 0; c < 14; c += 2) {
      stageA(A1, c + 1);
      qload(c + 2, qA);
      compute(A0, B0);
      writesB(qB, B1);
      asm volatile("s_waitcnt vmcnt(2)" ::: "memory");
      __builtin_amdgcn_sched_barrier(0);
      asm volatile("s_waitcnt lgkmcnt(0)" ::: "memory");
      __builtin_amdgcn_s_barrier();

      stageA(A0, c + 2);
      qload(c + 3, qB);
      compute(A1, B1);
      writesB(qA, B0);
      asm volatile("s_waitcnt vmcnt(2)" ::: "memory");
      __builtin_amdgcn_sched_barrier(0);
      asm volatile("s_waitcnt lgkmcnt(0)" ::: "memory");
      __builtin_amdgcn_s_barrier();
    }
    // chunk 14
    stageA(A1, 15);
    compute(A0, B0);
    writesB(qB, B1);
    asm volatile("s_waitcnt vmcnt(0)" ::: "memory");
    __builtin_amdgcn_sched_barrier(0);
    asm volatile("s_waitcnt lgkmcnt(0)" ::: "memory");
    __builtin_amdgcn_s_barrier();
    // chunk 15
    compute(A1, B1);
    __syncthreads();
    // acc -> Xs fp32 [128 m_ri][272B rows], XOR ((row>>3)&7)<<4
#pragma unroll
    for (int fm = 0; fm < 2; ++fm)
#pragma unroll
      for (int r4 = 0; r4 < 4; ++r4) {
        int row = mh * 32 + fm * 16 + (lane >> 4) * 4 + r4;
        int col = ehh * 16 + (lane & 15);
        int off = (row * 272 + col * 4) ^ (((row >> 3) & 7) << 4);
        *(float*)(smem + off) = acc[fm][r4];
      }
  }
  __syncthreads();

  // ================= P2: mix (fp32 VALU, bf16 W from L2) =================
  {
    char* OtB = smem + 34816;          // [64 o][128 m_ri] bf16, 256B rows, XOR (o&15)<<4
    int o = t >> 4, mq = t & 15;       // thread: 1 o, 4 m (m = mq*4+mi)
    const unsigned short* wbr = WBr + (size_t)h * 262144 + o * 64 + mq * 4;
    const unsigned short* wbi = WBi + (size_t)h * 262144 + o * 64 + mq * 4;
    float orr[4] = {}, oii[4] = {};
    for (int ib = 0; ib < 16; ++ib) {
      f32x4 xr4[4], xi4[4];
#pragma unroll
      for (int mi = 0; mi < 4; ++mi) {
        int m = mq * 4 + mi;
        xr4[mi] = *(const f32x4*)(smem + ((m * 272 + ib * 16) ^ (((m >> 3) & 7) << 4)));
        xi4[mi] = *(const f32x4*)(smem + (((64 + m) * 272 + ib * 16) ^ (((m >> 3) & 7) << 4)));
      }
      us4 wr4[4], wi4[4];
#pragma unroll
      for (int ii = 0; ii < 4; ++ii) {
        int i = ib * 4 + ii;
        wr4[ii] = *(const us4*)(wbr + (size_t)i * 4096);
        wi4[ii] = *(const us4*)(wbi + (size_t)i * 4096);
      }
#pragma unroll
      for (int ii = 0; ii < 4; ++ii)
#pragma unroll
        for (int mi = 0; mi < 4; ++mi) {
          float wrv = bf2f(wr4[ii][mi]);
          float wiv = bf2f(wi4[ii][mi]);
          orr[mi] += xr4[mi][ii] * wrv - xi4[mi][ii] * wiv;
          oii[mi] += xr4[mi][ii] * wiv + xi4[mi][ii] * wrv;
        }
    }
    uint2 vr = make_uint2(pk2(orr[0], orr[1]), pk2(orr[2], orr[3]));
    uint2 vi = make_uint2(pk2(oii[0], oii[1]), pk2(oii[2], oii[3]));
    *(uint2*)(OtB + ((o * 256 + mq * 8) ^ ((o & 15) << 4))) = vr;
    *(uint2*)(OtB + ((o * 256 + 128 + mq * 8) ^ ((o & 15) << 4))) = vi;
  }
  __syncthreads();

  // ================= P3: iDFT  out = Ot * IT^T =================
  {
    const char* OtB = smem + 34816;
    bf16x8 af[2][8];
#pragma unroll
    for (int rg2 = 0; rg2 < 2; ++rg2)
#pragma unroll
      for (int ks = 0; ks < 8; ++ks) {
        int row = rg2 * 32 + (lane & 31);
        int off = (row * 256 + ks * 32 + (lane >> 5) * 16) ^ ((row & 15) << 4);
        af[rg2][ks] = __builtin_bit_cast(bf16x8, *(const us8*)(OtB + off));
      }
    float* ob = out + ((size_t)(b * 8 + h) * 64) * NL;
    int l0 = wid * 128;
    for (int ct = 0; ct < 4; ++ct) {
      int lr = l0 + ct * 32 + (lane & 31);
      f32x16 aE[2] = {}, aO[2] = {};   // even/odd-ks chains (4 independent)
#pragma unroll
      for (int ks = 0; ks < 8; ks += 2) {
        bf16x8 bv0 = __builtin_bit_cast(
            bf16x8, *(const us8*)(IT + (size_t)lr * MRI + ks * 16 + (lane >> 5) * 8));
        bf16x8 bv1 = __builtin_bit_cast(
            bf16x8, *(const us8*)(IT + (size_t)lr * MRI + (ks + 1) * 16 + (lane >> 5) * 8));
        aE[0] = __builtin_amdgcn_mfma_f32_32x32x16_bf16(af[0][ks], bv0, aE[0], 0, 0, 0);
        aE[1] = __builtin_amdgcn_mfma_f32_32x32x16_bf16(af[1][ks], bv0, aE[1], 0, 0, 0);
        aO[0] = __builtin_amdgcn_mfma_f32_32x32x16_bf16(af[0][ks + 1], bv1, aO[0], 0, 0, 0);
        aO[1] = __builtin_amdgcn_mfma_f32_32x32x16_bf16(af[1][ks + 1], bv1, aO[1], 0, 0, 0);
      }
#pragma unroll
      for (int rg2 = 0; rg2 < 2; ++rg2) {
        f32x16 a2 = aE[rg2] + aO[rg2];
#pragma unroll
        for (int rg = 0; rg < 16; ++rg) {
          int row = rg2 * 32 + ((rg & 3) + 8 * (rg >> 2) + 4 * (lane >> 5));
          ob[(size_t)row * NL + lr] = a2[rg];
        }
      }
    }
  }
}

extern "C" void kernel_launch(void* const* d_in, const int* in_sizes, int n_in,
                              void* d_out, int out_size, void* d_ws, size_t ws_size,
                              hipStream_t stream) {
  const float* q = (const float*)d_in[0];
  const float* wr = (const float*)d_in[3];
  const float* wi = (const float*)d_in[4];
  const int* idx = (const int*)d_in[5];
  float* out = (float*)d_out;
  char* ws = (char*)d_ws;

  constexpr size_t TBYTES = (size_t)MRI * NL * 2;            // 512 KB per table
  constexpr size_t WBBYTES = (size_t)NH * NE * NE * NM * 2;  // 4 MB per comp
  constexpr size_t NEED = 2 * TBYTES + 2 * WBBYTES;
  if (ws_size < NEED) return;

  unsigned short* T = (unsigned short*)ws;
  unsigned short* IT = (unsigned short*)(ws + TBYTES);
  unsigned short* WBr = (unsigned short*)(ws + 2 * TBYTES);
  unsigned short* WBi = (unsigned short*)(ws + 2 * TBYTES + WBBYTES);

  hipLaunchKernelGGL(tables_k, dim3(1024), dim3(256), 0, stream, idx, wr, wi, T, IT, WBr, WBi);
  hipLaunchKernelGGL(fused_k, dim3(NB * NH), dim3(1024), 0, stream, q, T, IT, WBr, WBi, out);
}

// Round 12
// 85.355 us; speedup vs baseline: 1.2016x; 1.1754x over previous
//
#include <hip/hip_runtime.h>
#include <math.h>

#define NB 32
#define NL 2048
#define NH 8
#define NE 64
#define NM 64
#define MRI 128          // 2*NM (re stacked over im)
#define BK 128           // K per chunk
#define NCH 16           // 2048 / BK

typedef __attribute__((ext_vector_type(8))) __bf16 bf16x8;
typedef __attribute__((ext_vector_type(2))) __bf16 bf16x2;
typedef __attribute__((ext_vector_type(8))) unsigned short us8;
typedef __attribute__((ext_vector_type(4))) unsigned short us4;
typedef __attribute__((ext_vector_type(4))) float f32x4;
typedef __attribute__((ext_vector_type(16))) float f32x16;

__device__ __forceinline__ unsigned short f2bf(float x) {
  unsigned int u = __builtin_bit_cast(unsigned int, x);
  u = (u + 0x7fffu + ((u >> 16) & 1u)) >> 16;
  return (unsigned short)u;
}
__device__ __forceinline__ float bf2f(unsigned short u) {
  return __builtin_bit_cast(float, (unsigned int)u << 16);
}
__device__ __forceinline__ unsigned int pk2(float lo, float hi) {
  bf16x2 v;
  v[0] = (__bf16)lo;
  v[1] = (__bf16)hi;
  return __builtin_bit_cast(unsigned int, v);
}
__device__ __forceinline__ void gll16(const void* g, void* l) {
  __builtin_amdgcn_global_load_lds(
      (const __attribute__((address_space(1))) void*)g,
      (__attribute__((address_space(3))) void*)l, 16, 0, 0);
}

// ---------------- tables + W->bf16 ----------------
__global__ void tables_k(const int* __restrict__ idx,
                         const float* __restrict__ wr, const float* __restrict__ wi,
                         unsigned short* __restrict__ T, unsigned short* __restrict__ IT,
                         unsigned short* __restrict__ WBr, unsigned short* __restrict__ WBi) {
  int gid = blockIdx.x * blockDim.x + threadIdx.x;  // 0..262143
  const float w0 = 6.283185307179586f / (float)NL;
  {
    int row = gid >> 11, l = gid & (NL - 1);
    int m = row & 63;
    int f = idx[m];
    float s, c;
    sincosf((float)((f * l) & (NL - 1)) * w0, &s, &c);
    T[gid] = f2bf(row < 64 ? c : -s);
  }
  {
    int lp = gid >> 7, k = gid & 127;
    int m = k & 63;
    float s, c;
    sincosf((float)((m * lp) & (NL - 1)) * w0, &s, &c);
    float v = (k < 64) ? ((m == 0 ? 1.0f : 2.0f) / (float)NL) * c
                       : (m == 0 ? 0.0f : (-2.0f / (float)NL) * s);
    IT[gid] = f2bf(v);
  }
  {
    const float2* wr2 = (const float2*)wr;
    const float2* wi2 = (const float2*)wi;
    unsigned int* obr = (unsigned int*)WBr;
    unsigned int* obi = (unsigned int*)WBi;
#pragma unroll
    for (int r = 0; r < 4; ++r) {
      int j = r * 262144 + gid;
      float2 a = wr2[j];
      float2 b2 = wi2[j];
      obr[j] = pk2(a.x, a.y);
      obi[j] = pk2(b2.x, b2.y);
    }
  }
}

// ---------------- fused per-(b,h), 256 blocks x 1024 thr ----------------
// LDS map: Ab dbuf 2x32768 @0 (256B rows, XOR (row&7)<<4)
//          Bb dbuf 2x16896 @65536 ([e 64][l 128] bf16, 264B rows)
//          after P1: scratch partials @65536 ; Xs [128][272B] @0 ; OtB @34816
__global__ __launch_bounds__(1024) void fused_k(const float* __restrict__ q,
                                                const unsigned short* __restrict__ T,
                                                const unsigned short* __restrict__ IT,
                                                const unsigned short* __restrict__ WBr,
                                                const unsigned short* __restrict__ WBi,
                                                float* __restrict__ out) {
  __shared__ __align__(16) char smem[99328];
  int t = threadIdx.x, lane = t & 63, wid = t >> 6;
  int h = blockIdx.x & 7, b = blockIdx.x >> 3;

  // ================= P1: DFT  X = T * q  (32x32x16 MFMA, K-half wave split) =================
  {
    char* Ab = smem;            // 2 x 32768, rows 256B, XOR (row&7)<<4
    char* B0 = smem + 65536;    // rows 264B
    char* B1 = smem + 65536 + 16896;
    const float* qb = q + ((size_t)b * NL * NH + h) * NE;  // q[b][l][h][e]
    int tm = wid & 3;           // m-group of 32 rows
    int te = (wid >> 2) & 1;    // e-group of 32 cols
    int kh = wid >> 3;          // K-half (0: k 0-63, 1: k 64-127 within chunk)
    int eq = t & 15, lq = t >> 4;   // staging: e-quad (coalesced), l-pair
    f32x16 acc32 = {};
    f32x4 qA[2], qB[2];

    auto qload = [&](int c, f32x4* qr) {
#pragma unroll
      for (int p = 0; p < 2; ++p)
        qr[p] = *(const f32x4*)(qb + (size_t)(c * BK + lq * 2 + p) * (NH * NE) + eq * 4);
    };
    auto writesB = [&](const f32x4* qr, char* bb) {
#pragma unroll
      for (int j = 0; j < 4; ++j) {
        int e = eq * 4 + j;
        *(unsigned int*)(bb + e * 264 + lq * 4) = pk2(qr[0][j], qr[1][j]);
      }
    };
    auto stageA = [&](int bufi, int c) {
#pragma unroll
      for (int n = 0; n < 2; ++n) {
        int lin = n * 16384 + t * 16;
        int row = lin >> 8;
        int colb = (lin & 255) ^ ((row & 7) << 4);   // pre-swizzled source
        gll16((const char*)T + (size_t)row * (NL * 2) + (size_t)c * 256 + colb,
              Ab + bufi * 32768 + lin);
      }
    };
    auto compute = [&](const char* ab, const char* bb) {
#pragma unroll
      for (int ks = 0; ks < 4; ++ks) {
        int k0 = (kh * 4 + ks) * 16;
        int e = te * 32 + (lane & 31);
        int boff = e * 264 + (k0 + (lane >> 5) * 8) * 2;
        uint2 blo = *(const uint2*)(bb + boff);
        uint2 bhi = *(const uint2*)(bb + boff + 8);
        bf16x8 bfr = __builtin_bit_cast(bf16x8, make_uint4(blo.x, blo.y, bhi.x, bhi.y));
        int row = tm * 32 + (lane & 31);
        int aoff = (row * 256 + (k0 + (lane >> 5) * 8) * 2) ^ ((row & 7) << 4);
        bf16x8 afr = __builtin_bit_cast(bf16x8, *(const us8*)(ab + aoff));
        acc32 = __builtin_amdgcn_mfma_f32_32x32x16_bf16(afr, bfr, acc32, 0, 0, 0);
      }
    };

    // prologue (round-9 schedule, unchanged)
    qload(0, qA);
    qload(1, qB);
    stageA(0, 0);
    writesB(qA, B0);
    asm volatile("s_waitcnt vmcnt(0)" ::: "memory");
    __builtin_amdgcn_sched_barrier(0);
    asm volatile("s_waitcnt lgkmcnt(0)" ::: "memory");
    __builtin_amdgcn_s_barrier();
    for (int c = 0; c < 14; c += 2) {
      stageA(1, c + 1);
      qload(c + 2, qA);
      compute(Ab, B0);
      asm volatile("s_waitcnt vmcnt(2)" ::: "memory");
      __builtin_amdgcn_sched_barrier(0);
      __builtin_amdgcn_s_barrier();
      writesB(qB, B1);
      asm volatile("s_waitcnt lgkmcnt(0)" ::: "memory");
      __builtin_amdgcn_s_barrier();

      stageA(0, c + 2);
      qload(c + 3, qB);
      compute(Ab + 32768, B1);
      asm volatile("s_waitcnt vmcnt(2)" ::: "memory");
      __builtin_amdgcn_sched_barrier(0);
      __builtin_amdgcn_s_barrier();
      writesB(qA, B0);
      asm volatile("s_waitcnt lgkmcnt(0)" ::: "memory");
      __builtin_amdgcn_s_barrier();
    }
    // chunk 14
    stageA(1, 15);
    compute(Ab, B0);
    asm volatile("s_waitcnt vmcnt(0)" ::: "memory");
    __builtin_amdgcn_sched_barrier(0);
    __builtin_amdgcn_s_barrier();
    writesB(qB, B1);
    asm volatile("s_waitcnt lgkmcnt(0)" ::: "memory");
    __builtin_amdgcn_s_barrier();
    // chunk 15
    compute(Ab + 32768, B1);
    __syncthreads();

    // K-half merge via scratch (over dead B-buf region), then Xs write
    float* scr = (float*)(smem + 65536);  // 8 tiles x 32x32 f32 = 32 KB
    int tile = wid & 7;
    if (kh == 1) {
#pragma unroll
      for (int r = 0; r < 16; ++r) {
        int row = (r & 3) + 8 * (r >> 2) + 4 * (lane >> 5);
        scr[tile * 1024 + row * 32 + (lane & 31)] = acc32[r];
      }
    }
    __syncthreads();
    if (kh == 0) {
#pragma unroll
      for (int r = 0; r < 16; ++r) {
        int row = (r & 3) + 8 * (r >> 2) + 4 * (lane >> 5);
        float v = acc32[r] + scr[tile * 1024 + row * 32 + (lane & 31)];
        int grow = tm * 32 + row;          // m_ri
        int gcol = te * 32 + (lane & 31);  // e
        int off = (grow * 272 + gcol * 4) ^ (((grow >> 3) & 7) << 4);
        *(float*)(smem + off) = v;
      }
    }
  }
  __syncthreads();

  // ================= P2: mix (fp32 VALU, bf16 W from L2) =================
  {
    char* OtB = smem + 34816;          // [64 o][128 m_ri] bf16, 256B rows, XOR (o&7)<<4
    int o = t >> 4, mq = t & 15;       // thread: 1 o, 4 m (m = mq*4+mi)
    const unsigned short* wbr = WBr + (size_t)h * 262144 + o * 64 + mq * 4;
    const unsigned short* wbi = WBi + (size_t)h * 262144 + o * 64 + mq * 4;
    float orr[4] = {}, oii[4] = {};
#pragma unroll 2
    for (int ib = 0; ib < 16; ++ib) {
      f32x4 xr4[4], xi4[4];
#pragma unroll
      for (int mi = 0; mi < 4; ++mi) {
        int m = mq * 4 + mi;
        xr4[mi] = *(const f32x4*)(smem + ((m * 272 + ib * 16) ^ (((m >> 3) & 7) << 4)));
        xi4[mi] = *(const f32x4*)(smem + (((64 + m) * 272 + ib * 16) ^ (((m >> 3) & 7) << 4)));
      }
      us4 wr4[4], wi4[4];
#pragma unroll
      for (int ii = 0; ii < 4; ++ii) {
        int i = ib * 4 + ii;
        wr4[ii] = *(const us4*)(wbr + (size_t)i * 4096);
        wi4[ii] = *(const us4*)(wbi + (size_t)i * 4096);
      }
#pragma unroll
      for (int ii = 0; ii < 4; ++ii)
#pragma unroll
        for (int mi = 0; mi < 4; ++mi) {
          float wrv = bf2f(wr4[ii][mi]);
          float wiv = bf2f(wi4[ii][mi]);
          orr[mi] += xr4[mi][ii] * wrv - xi4[mi][ii] * wiv;
          oii[mi] += xr4[mi][ii] * wiv + xi4[mi][ii] * wrv;
        }
    }
    uint2 vr = make_uint2(pk2(orr[0], orr[1]), pk2(orr[2], orr[3]));
    uint2 vi = make_uint2(pk2(oii[0], oii[1]), pk2(oii[2], oii[3]));
    *(uint2*)(OtB + ((o * 256 + mq * 8) ^ ((o & 7) << 4))) = vr;
    *(uint2*)(OtB + ((o * 256 + 128 + mq * 8) ^ ((o & 7) << 4))) = vi;
  }
  __syncthreads();

  // ================= P3: iDFT  out = Ot * IT^T =================
  {
    const char* OtB = smem + 34816;
    bf16x8 af[2][8];
#pragma unroll
    for (int rg2 = 0; rg2 < 2; ++rg2)
#pragma unroll
      for (int ks = 0; ks < 8; ++ks) {
        int row = rg2 * 32 + (lane & 31);
        int off = (row * 256 + ks * 32 + (lane >> 5) * 16) ^ ((row & 7) << 4);
        af[rg2][ks] = __builtin_bit_cast(bf16x8, *(const us8*)(OtB + off));
      }
    float* ob = out + ((size_t)(b * 8 + h) * 64) * NL;
    int l0 = wid * 128;
    for (int ct = 0; ct < 4; ++ct) {
      int lr = l0 + ct * 32 + (lane & 31);
      f32x16 a2[2] = {};
#pragma unroll
      for (int ks = 0; ks < 8; ++ks) {
        bf16x8 bv = __builtin_bit_cast(
            bf16x8, *(const us8*)(IT + (size_t)lr * MRI + ks * 16 + (lane >> 5) * 8));
        a2[0] = __builtin_amdgcn_mfma_f32_32x32x16_bf16(af[0][ks], bv, a2[0], 0, 0, 0);
        a2[1] = __builtin_amdgcn_mfma_f32_32x32x16_bf16(af[1][ks], bv, a2[1], 0, 0, 0);
      }
#pragma unroll
      for (int rg2 = 0; rg2 < 2; ++rg2)
#pragma unroll
        for (int rg = 0; rg < 16; ++rg) {
          int row = rg2 * 32 + ((rg & 3) + 8 * (rg >> 2) + 4 * (lane >> 5));
          ob[(size_t)row * NL + lr] = a2[rg2][rg];
        }
    }
  }
}

extern "C" void kernel_launch(void* const* d_in, const int* in_sizes, int n_in,
                              void* d_out, int out_size, void* d_ws, size_t ws_size,
                              hipStream_t stream) {
  const float* q = (const float*)d_in[0];
  const float* wr = (const float*)d_in[3];
  const float* wi = (const float*)d_in[4];
  const int* idx = (const int*)d_in[5];
  float* out = (float*)d_out;
  char* ws = (char*)d_ws;

  constexpr size_t TBYTES = (size_t)MRI * NL * 2;            // 512 KB per table
  constexpr size_t WBBYTES = (size_t)NH * NE * NE * NM * 2;  // 4 MB per comp
  constexpr size_t NEED = 2 * TBYTES + 2 * WBBYTES;
  if (ws_size < NEED) return;

  unsigned short* T = (unsigned short*)ws;
  unsigned short* IT = (unsigned short*)(ws + TBYTES);
  unsigned short* WBr = (unsigned short*)(ws + 2 * TBYTES);
  unsigned short* WBi = (unsigned short*)(ws + 2 * TBYTES + WBBYTES);

  hipLaunchKernelGGL(tables_k, dim3(1024), dim3(256), 0, stream, idx, wr, wi, T, IT, WBr, WBi);
  hipLaunchKernelGGL(fused_k, dim3(NB * NH), dim3(1024), 0, stream, q, T, IT, WBr, WBi, out);
}